// Round 2
// baseline (617.316 us; speedup 1.0000x reference)
//
#include <hip/hip_runtime.h>
#include <hip/hip_fp16.h>
#include <math.h>
#include <stdint.h>
#include <type_traits>

#define NN   100000
#define EE   1200000
#define GG   128
#define FIN  16
#define HH   64
#define OUTF 5
#define NHID 3

#define CE   4096                       // edges per block in bucket phases
#define EB   ((EE + CE - 1) / CE)       // 293 edge-blocks
#define NBUK ((NN + 511) >> 9)          // 196 buckets of 512 nodes
#define LEN  (NBUK * EB)                // hblk/eoff length

typedef _Float16 f16x8 __attribute__((ext_vector_type(8)));
typedef float f32x4 __attribute__((ext_vector_type(4)));

// ---------------- wave helpers ----------------
static __device__ __forceinline__ float wave_reduce_sum(float p) {
#pragma unroll
  for (int m = 32; m >= 1; m >>= 1) p += __shfl_xor(p, m, 64);
  return p;
}

// ---------------- bucketed CSR build ----------------
__global__ void k_bh(const int* __restrict__ ei, int* __restrict__ hblk) {
  __shared__ int h[NBUK];
  int tid = threadIdx.x, blk = blockIdx.x;
  for (int i = tid; i < NBUK; i += 256) h[i] = 0;
  __syncthreads();
  int base = blk * CE;
  for (int i = tid; i < CE; i += 256) {
    int e = base + i;
    if (e < EE) atomicAdd(&h[ei[EE + e] >> 9], 1);
  }
  __syncthreads();
  for (int i = tid; i < NBUK; i += 256) hblk[i * EB + blk] = h[i];
}

__global__ void k_scan1(const int* __restrict__ in, int* __restrict__ incl,
                        int* __restrict__ bsum, int n) {
  __shared__ int sd[256];
  int t = threadIdx.x, blk = blockIdx.x;
  int base = blk * 1024 + t * 4;
  int v[4];
#pragma unroll
  for (int i = 0; i < 4; i++) v[i] = (base + i < n) ? in[base + i] : 0;
  int s = v[0] + v[1] + v[2] + v[3];
  sd[t] = s;
  __syncthreads();
  for (int off = 1; off < 256; off <<= 1) {
    int x = 0;
    if (t >= off) x = sd[t - off];
    __syncthreads();
    if (t >= off) sd[t] += x;
    __syncthreads();
  }
  int run = sd[t] - s;
#pragma unroll
  for (int i = 0; i < 4; i++) {
    run += v[i];
    if (base + i < n) incl[base + i] = run;
  }
  if (t == 255) bsum[blk] = sd[255];
}

__global__ void k_scan2(const int* __restrict__ bsum, int* __restrict__ boff, int nb) {
  if (threadIdx.x == 0 && blockIdx.x == 0) {
    int run = 0;
    for (int i = 0; i < nb; i++) { boff[i] = run; run += bsum[i]; }
  }
}

__global__ void k_eoff(const int* __restrict__ incl, const int* __restrict__ boff,
                       const int* __restrict__ hblk, int* __restrict__ eoff, int n) {
  int t = blockIdx.x * blockDim.x + threadIdx.x;
  if (t < n) eoff[t] = incl[t] + boff[t / 1024] - hblk[t];
}

__global__ void k_binwrite(const int* __restrict__ ei, const int* __restrict__ eoff,
                           int2* __restrict__ ebuf) {
  __shared__ int cur[NBUK];
  int tid = threadIdx.x, blk = blockIdx.x;
  for (int i = tid; i < NBUK; i += 256) cur[i] = eoff[i * EB + blk];
  __syncthreads();
  int base = blk * CE;
  for (int i = tid; i < CE; i += 256) {
    int e = base + i;
    if (e < EE) {
      int d = ei[EE + e];
      int s = ei[e];
      int p = atomicAdd(&cur[d >> 9], 1);
      ebuf[p] = make_int2(s, d);
    }
  }
}

// merged bdeg2 + binscatter (R16-verified): histogram -> scan -> row_ptr ->
// cursors -> scatter col, all in one block per 512-node bucket.
__global__ void k_bcsr(const int2* __restrict__ ebuf, const int* __restrict__ eoff,
                       int* __restrict__ row_ptr, int* __restrict__ col, int n) {
  __shared__ int dl[512];
  __shared__ int ps[256];
  int b = blockIdx.x, tid = threadIdx.x;
  int d0 = b << 9;
  dl[tid] = 0; dl[tid + 256] = 0;
  __syncthreads();
  int s0 = eoff[b * EB];
  int s1 = (b + 1 < NBUK) ? eoff[(b + 1) * EB] : EE;
  for (int e = s0 + tid; e < s1; e += 256) atomicAdd(&dl[ebuf[e].y - d0], 1);
  __syncthreads();
  int a0 = dl[2 * tid], a1 = dl[2 * tid + 1];
  ps[tid] = a0 + a1;
  __syncthreads();
  for (int off = 1; off < 256; off <<= 1) {
    int x = 0;
    if (tid >= off) x = ps[tid - off];
    __syncthreads();
    if (tid >= off) ps[tid] += x;
    __syncthreads();
  }
  int epair = ps[tid] - (a0 + a1);     // exclusive prefix of this pair
  int r0 = s0 + epair;
  int r1 = r0 + a0;
  int i0 = d0 + 2 * tid;
  if (i0 <= n) row_ptr[i0] = r0;       // covers row_ptr[n] = EE
  if (i0 + 1 <= n) row_ptr[i0 + 1] = r1;
  __syncthreads();
  dl[2 * tid] = r0;                    // reuse histogram LDS as cursors
  dl[2 * tid + 1] = r1;
  __syncthreads();
  for (int e = s0 + tid; e < s1; e += 256) {
    int2 sd = ebuf[e];
    int p = atomicAdd(&dl[sd.y - d0], 1);
    col[p] = sd.x;
  }
}

// ---------------- projections via MFMA ----------------
template <int F, typename TIN>
__global__ __launch_bounds__(256) void k_gemm_mfma(
    const TIN* __restrict__ X,
    const float* __restrict__ Wq, const float* __restrict__ bq,
    const float* __restrict__ Wk, const float* __restrict__ bk,
    const float* __restrict__ Wv, const float* __restrict__ bv,
    const float* __restrict__ Ws, const float* __restrict__ bs,
    __half* __restrict__ qh, __half* __restrict__ kh, __half* __restrict__ vh,
    __half* __restrict__ Bh, int n) {
  constexpr int KH = (F + 31) / 32;
  constexpr int S = KH * 32 + 8;
  __shared__ _Float16 xs[64 * S];
  int tid = threadIdx.x;
  int lane = tid & 63;
  int wv = tid >> 6;
  int quad = lane >> 4;
  int li = lane & 15;
  int node0 = blockIdx.x * 64;

  if constexpr (std::is_same<TIN, float>::value) {
    constexpr int F4 = F / 4;
    constexpr int CNT = 64 * F4 / 256;
#pragma unroll
    for (int i = 0; i < CNT; i++) {
      int idx = tid + i * 256;
      int nd = idx / F4;
      int kb = (idx % F4) * 4;
      float4 p;
      if (node0 + nd < n) p = *(const float4*)(X + (size_t)(node0 + nd) * F + kb);
      else p = make_float4(0.f, 0.f, 0.f, 0.f);
      _Float16* d = xs + nd * S + kb;
      d[0] = (_Float16)p.x; d[1] = (_Float16)p.y;
      d[2] = (_Float16)p.z; d[3] = (_Float16)p.w;
    }
    if (F == 16) {  // zero-pad k in [16,32)
      int nd = tid >> 2;
      int kb = 16 + (tid & 3) * 4;
      _Float16* d = xs + nd * S + kb;
      d[0] = 0; d[1] = 0; d[2] = 0; d[3] = 0;
    }
  } else {
    constexpr int F8 = F / 8;
    constexpr int CNT = 64 * F8 / 256;
#pragma unroll
    for (int i = 0; i < CNT; i++) {
      int idx = tid + i * 256;
      int nd = idx / F8;
      int kb = (idx % F8) * 8;
      f16x8 p = {};
      if (node0 + nd < n)
        p = *(const f16x8*)((const _Float16*)X + (size_t)(node0 + nd) * F + kb);
      *(f16x8*)(xs + nd * S + kb) = p;
    }
  }

  const float* W; const float* bias;
  if (wv == 0)      { W = Wq; bias = bq; }
  else if (wv == 1) { W = Wk; bias = bk; }
  else if (wv == 2) { W = Wv; bias = bv; }
  else              { W = Ws; bias = bs; }

  f16x8 bf[4][KH];
#pragma unroll
  for (int ns = 0; ns < 4; ns++)
#pragma unroll
    for (int kh2 = 0; kh2 < KH; kh2++)
#pragma unroll
      for (int j = 0; j < 8; j++) {
        int kidx = kh2 * 32 + quad * 8 + j;
        bf[ns][kh2][j] = (kidx < F)
            ? (_Float16)W[(size_t)kidx * 64 + ns * 16 + li] : (_Float16)0.f;
      }
  float blv[4];
#pragma unroll
  for (int ns = 0; ns < 4; ns++) blv[ns] = bias[ns * 16 + li];

  __syncthreads();

  f16x8 af[4][KH];
#pragma unroll
  for (int ms = 0; ms < 4; ms++)
#pragma unroll
    for (int kh2 = 0; kh2 < KH; kh2++)
      af[ms][kh2] = *(const f16x8*)(xs + (ms * 16 + li) * S + kh2 * 32 + quad * 8);

  f32x4 acc[4][4];
#pragma unroll
  for (int ms = 0; ms < 4; ms++)
#pragma unroll
    for (int ns = 0; ns < 4; ns++) {
      float b = blv[ns];
      acc[ms][ns] = (f32x4){b, b, b, b};
    }
#pragma unroll
  for (int kh2 = 0; kh2 < KH; kh2++)
#pragma unroll
    for (int ms = 0; ms < 4; ms++)
#pragma unroll
      for (int ns = 0; ns < 4; ns++)
        acc[ms][ns] = __builtin_amdgcn_mfma_f32_16x16x32_f16(
            af[ms][kh2], bf[ns][kh2], acc[ms][ns], 0, 0, 0);

  __half* outh = (wv == 0) ? qh : (wv == 1) ? kh : (wv == 2) ? vh : Bh;
#pragma unroll
  for (int ms = 0; ms < 4; ms++)
#pragma unroll
    for (int ns = 0; ns < 4; ns++) {
      int colc = ns * 16 + li;
#pragma unroll
      for (int r = 0; r < 4; r++) {
        int node = node0 + ms * 16 + quad * 4 + r;
        if (node < n)
          outh[(size_t)node * 64 + colc] = __float2half(acc[ms][ns][r]);
      }
    }
}

// ---------------- fused attention, edge-dense (R17) ----------------
// Block = 64 consecutive dsts, edges CSR-contiguous (M ~ 768 +- 28).
// 32 groups x 8 lanes walk contiguous ~24-edge strips; per edge the 8
// lanes cooperatively gather k[src] AND v[src] (2x128B), dot against a
// register-cached q row (reloaded from LDS only on dst advance), shfl-
// reduce over 8 lanes, exp, accumulate pe*v in registers; flush to LDS
// accumulator at dst boundaries (~2 per strip). exp without max-subtract
// is associative, so partial strips compose via LDS atomics.
__global__ __launch_bounds__(256) void k_fused(
    const __half* __restrict__ qh, const __half* __restrict__ kh,
    const __half* __restrict__ vh, const int* __restrict__ row_ptr,
    const int* __restrict__ col, __half* __restrict__ Bh, int n) {
  __shared__ _Float16 qs[64 * 72];     // q rows, stride-padded
  __shared__ float accs[64 * 68];      // [dst_local][dim], stride-padded
  __shared__ float denom[64];
  __shared__ int rpl[65];
  int tid = threadIdx.x;
  int d0 = blockIdx.x * 64;
  int ndst = n - d0; if (ndst > 64) ndst = 64;

  {
    __half2 z = __floats2half2_rn(0.f, 0.f);
#pragma unroll
    for (int i = 0; i < 8; i++) {      // 2048 half2 slots
      int idx = tid + i * 256;
      int r = idx >> 5, cp = idx & 31;
      __half2 v = (r < ndst) ? ((const __half2*)(qh + (size_t)(d0 + r) * 64))[cp] : z;
      *(__half2*)(qs + r * 72 + cp * 2) = v;
    }
  }
  for (int i = tid; i < 64 * 68; i += 256) accs[i] = 0.f;
  if (tid < 64) denom[tid] = 0.f;
  if (tid < 65) { int dd = d0 + tid; rpl[tid] = row_ptr[dd > n ? n : dd]; }
  __syncthreads();

  int e0 = rpl[0], e1 = rpl[ndst];
  int M = e1 - e0;
  if (M > 0) {
    int L = (M + 31) >> 5;             // strip length per 8-lane group
    int g = tid >> 3, j = tid & 7;
    int s = e0 + g * L;
    int send = s + L; if (send > e1) send = e1;
    if (s < send) {
      int lo = 0, hi = ndst;           // binary search: rpl[lo] <= s < rpl[lo+1]
      while (hi - lo > 1) {
        int mid = (lo + hi) >> 1;
        if (rpl[mid] <= s) lo = mid; else hi = mid;
      }
      int dl = lo;
      f16x8 qv = *(const f16x8*)(qs + dl * 72 + j * 8);
      float vacc[8];
#pragma unroll
      for (int t = 0; t < 8; t++) vacc[t] = 0.f;
      float dacc = 0.f;
      for (int e = s; e < send; e++) {
        if (e >= rpl[dl + 1]) {        // dst boundary: flush + advance
#pragma unroll
          for (int t = 0; t < 8; t++) atomicAdd(&accs[dl * 68 + j * 8 + t], vacc[t]);
          if (j == 0) atomicAdd(&denom[dl], dacc);
#pragma unroll
          for (int t = 0; t < 8; t++) vacc[t] = 0.f;
          dacc = 0.f;
          do { dl++; } while (e >= rpl[dl + 1]);
          qv = *(const f16x8*)(qs + dl * 72 + j * 8);
        }
        int src = col[e];
        f16x8 kv = *(const f16x8*)((const _Float16*)kh + (size_t)src * 64 + j * 8);
        f16x8 vv = *(const f16x8*)((const _Float16*)vh + (size_t)src * 64 + j * 8);
        float ds = 0.f;
#pragma unroll
        for (int u = 0; u < 8; u++) ds += (float)qv[u] * (float)kv[u];
        ds += __shfl_xor(ds, 1, 64);
        ds += __shfl_xor(ds, 2, 64);
        ds += __shfl_xor(ds, 4, 64);
        float pe = __expf(fminf(ds * 0.125f, 60.f));   // 1/sqrt(64)
        dacc += pe;
#pragma unroll
        for (int t = 0; t < 8; t++) vacc[t] = fmaf(pe, (float)vv[t], vacc[t]);
      }
#pragma unroll
      for (int t = 0; t < 8; t++) atomicAdd(&accs[dl * 68 + j * 8 + t], vacc[t]);
      if (j == 0) atomicAdd(&denom[dl], dacc);
    }
  }
  __syncthreads();
#pragma unroll
  for (int i = 0; i < 16; i++) {       // 4096 (dst,dim) cells
    int idx = tid + i * 256;
    int dl = idx >> 6, dim = idx & 63;
    if (dl < ndst) {
      size_t off = (size_t)(d0 + dl) * 64 + dim;
      float agg = accs[dl * 68 + dim] / (denom[dl] + 1e-16f);
      Bh[off] = __float2half(__half2float(Bh[off]) + agg);  // B pre-holds skip
    }
  }
}

// ---------------- pooling ----------------
__global__ __launch_bounds__(256) void k_pool(
    const __half* __restrict__ H, const int* __restrict__ batch,
    float* __restrict__ pooled, int* __restrict__ cnt, int n) {
  int lane = threadIdx.x & 63;
  int w = threadIdx.x >> 6;
  int n0 = blockIdx.x * 64 + w * 16;
  float acc = 0.f;
  int cur = -1, nc = 0;
  for (int i = 0; i < 16; i++) {
    int node = n0 + i;
    if (node >= n) break;
    int g = batch[node];
    if (g != cur) {
      if (cur >= 0) {
        atomicAdd(&pooled[cur * 64 + lane], acc);
        if (lane == 0) atomicAdd(&cnt[cur], nc);
      }
      cur = g;
      acc = 0.f;
      nc = 0;
    }
    acc += __half2float(H[(size_t)node * 64 + lane]);
    nc++;
  }
  if (cur >= 0) {
    atomicAdd(&pooled[cur * 64 + lane], acc);
    if (lane == 0) atomicAdd(&cnt[cur], nc);
  }
}

__global__ void k_out(const float* __restrict__ pooled, const int* __restrict__ cnt,
                      const float* __restrict__ Wf, const float* __restrict__ bf,
                      float* __restrict__ out) {
  int g = blockIdx.x;
  int lane = threadIdx.x;
  int c = cnt[g];
  float cf = (float)(c > 1 ? c : 1);
  float mean = pooled[g * 64 + lane] / cf;
#pragma unroll
  for (int o = 0; o < OUTF; o++) {
    float p = wave_reduce_sum(mean * Wf[lane * OUTF + o]);
    if (lane == 0) out[g * OUTF + o] = p + bf[o];
  }
}

// ---------------- launch ----------------
extern "C" void kernel_launch(void* const* d_in, const int* in_sizes, int n_in,
                              void* d_out, int out_size, void* d_ws, size_t ws_size,
                              hipStream_t stream) {
  const float* x   = (const float*)d_in[0];
  const int* ei    = (const int*)d_in[1];
  const int* batch = (const int*)d_in[2];
  const float *Wq0 = (const float*)d_in[3],  *bq0 = (const float*)d_in[4];
  const float *Wk0 = (const float*)d_in[5],  *bk0 = (const float*)d_in[6];
  const float *Wv0 = (const float*)d_in[7],  *bv0 = (const float*)d_in[8];
  const float *Ws0 = (const float*)d_in[9],  *bs0 = (const float*)d_in[10];
  const float *Wqh = (const float*)d_in[11], *bqh = (const float*)d_in[12];
  const float *Wkh = (const float*)d_in[13], *bkh = (const float*)d_in[14];
  const float *Wvh = (const float*)d_in[15], *bvh = (const float*)d_in[16];
  const float *Wsh = (const float*)d_in[17], *bsh = (const float*)d_in[18];
  const float *Wf  = (const float*)d_in[19], *bf  = (const float*)d_in[20];

  __half* qh = (__half*)d_ws;
  __half* kh = qh + (size_t)NN * 64;
  __half* vh = kh + (size_t)NN * 64;
  __half* B0 = vh + (size_t)NN * 64;
  __half* B1 = B0 + (size_t)NN * 64;
  float* pooled = (float*)(B1 + (size_t)NN * 64);
  int* cnt     = (int*)(pooled + GG * 64);
  int* row_ptr = cnt + GG;
  int* col     = row_ptr + NN + 2;
  int* hblk    = col + EE;
  int* incl2   = hblk + LEN;
  int* bsum2   = incl2 + LEN;
  int* boff2   = bsum2 + 128;
  int* eoff    = boff2 + 128;
  int2* ebuf   = (int2*)((((uintptr_t)(eoff + LEN)) + 15) & ~(uintptr_t)15);

  hipMemsetAsync(pooled, 0, (GG * 64 + GG) * sizeof(float), stream);

  // bucketed CSR build (once per call; reused by all 4 layers)
  k_bh<<<EB, 256, 0, stream>>>(ei, hblk);
  int nb2 = (LEN + 1023) / 1024;
  k_scan1<<<nb2, 256, 0, stream>>>(hblk, incl2, bsum2, LEN);
  k_scan2<<<1, 64, 0, stream>>>(bsum2, boff2, nb2);
  k_eoff<<<(LEN + 255) / 256, 256, 0, stream>>>(incl2, boff2, hblk, eoff, LEN);
  k_binwrite<<<EB, 256, 0, stream>>>(ei, eoff, ebuf);
  k_bcsr<<<NBUK, 256, 0, stream>>>(ebuf, eoff, row_ptr, col, NN);

  int gg = (NN + 63) / 64;
  int ga = (NN + 63) / 64;   // 64 dsts per block

  // layer 0 (F_IN=16, fp32 input)
  k_gemm_mfma<FIN, float><<<gg, 256, 0, stream>>>(
      x, Wq0, bq0, Wk0, bk0, Wv0, bv0, Ws0, bs0, qh, kh, vh, B0, NN);
  k_fused<<<ga, 256, 0, stream>>>(qh, kh, vh, row_ptr, col, B0, NN);

  // hidden layers (H=64, fp16 h), ping-pong B0 <-> B1
  const __half* hin = B0;
  __half* hout = B1;
  for (int i = 0; i < NHID; i++) {
    k_gemm_mfma<HH, __half><<<gg, 256, 0, stream>>>(
        hin, Wqh + i * 4096, bqh + i * 64,
        Wkh + i * 4096, bkh + i * 64,
        Wvh + i * 4096, bvh + i * 64,
        Wsh + i * 4096, bsh + i * 64,
        qh, kh, vh, hout, NN);
    k_fused<<<ga, 256, 0, stream>>>(qh, kh, vh, row_ptr, col, hout, NN);
    __half* t = (__half*)hin; hin = hout; hout = t;
  }

  k_pool<<<(NN + 63) / 64, 256, 0, stream>>>(hin, batch, pooled, cnt, NN);
  k_out<<<GG, 64, 0, stream>>>(pooled, cnt, Wf, bf, (float*)d_out);
}

// Round 3
// 475.090 us; speedup vs baseline: 1.2994x; 1.2994x over previous
//
#include <hip/hip_runtime.h>
#include <hip/hip_fp16.h>
#include <math.h>
#include <stdint.h>
#include <type_traits>

#define NN   100000
#define EE   1200000
#define GG   128
#define FIN  16
#define HH   64
#define OUTF 5
#define NHID 3

#define CE   4096                       // edges per block in bucket phases
#define EB   ((EE + CE - 1) / CE)       // 293 edge-blocks
#define NBUK ((NN + 511) >> 9)          // 196 buckets of 512 nodes
#define LEN  (NBUK * EB)                // hblk/eoff length

typedef _Float16 f16x8 __attribute__((ext_vector_type(8)));
typedef float f32x4 __attribute__((ext_vector_type(4)));

// ---------------- wave helpers ----------------
static __device__ __forceinline__ float wave_reduce_sum(float p) {
#pragma unroll
  for (int m = 32; m >= 1; m >>= 1) p += __shfl_xor(p, m, 64);
  return p;
}

// ---------------- bucketed CSR build ----------------
__global__ void k_bh(const int* __restrict__ ei, int* __restrict__ hblk) {
  __shared__ int h[NBUK];
  int tid = threadIdx.x, blk = blockIdx.x;
  for (int i = tid; i < NBUK; i += 256) h[i] = 0;
  __syncthreads();
  int base = blk * CE;
  for (int i = tid; i < CE; i += 256) {
    int e = base + i;
    if (e < EE) atomicAdd(&h[ei[EE + e] >> 9], 1);
  }
  __syncthreads();
  for (int i = tid; i < NBUK; i += 256) hblk[i * EB + blk] = h[i];
}

__global__ void k_scan1(const int* __restrict__ in, int* __restrict__ incl,
                        int* __restrict__ bsum, int n) {
  __shared__ int sd[256];
  int t = threadIdx.x, blk = blockIdx.x;
  int base = blk * 1024 + t * 4;
  int v[4];
#pragma unroll
  for (int i = 0; i < 4; i++) v[i] = (base + i < n) ? in[base + i] : 0;
  int s = v[0] + v[1] + v[2] + v[3];
  sd[t] = s;
  __syncthreads();
  for (int off = 1; off < 256; off <<= 1) {
    int x = 0;
    if (t >= off) x = sd[t - off];
    __syncthreads();
    if (t >= off) sd[t] += x;
    __syncthreads();
  }
  int run = sd[t] - s;
#pragma unroll
  for (int i = 0; i < 4; i++) {
    run += v[i];
    if (base + i < n) incl[base + i] = run;
  }
  if (t == 255) bsum[blk] = sd[255];
}

__global__ void k_scan2(const int* __restrict__ bsum, int* __restrict__ boff, int nb) {
  if (threadIdx.x == 0 && blockIdx.x == 0) {
    int run = 0;
    for (int i = 0; i < nb; i++) { boff[i] = run; run += bsum[i]; }
  }
}

__global__ void k_eoff(const int* __restrict__ incl, const int* __restrict__ boff,
                       const int* __restrict__ hblk, int* __restrict__ eoff, int n) {
  int t = blockIdx.x * blockDim.x + threadIdx.x;
  if (t < n) eoff[t] = incl[t] + boff[t / 1024] - hblk[t];
}

__global__ void k_binwrite(const int* __restrict__ ei, const int* __restrict__ eoff,
                           int2* __restrict__ ebuf) {
  __shared__ int cur[NBUK];
  int tid = threadIdx.x, blk = blockIdx.x;
  for (int i = tid; i < NBUK; i += 256) cur[i] = eoff[i * EB + blk];
  __syncthreads();
  int base = blk * CE;
  for (int i = tid; i < CE; i += 256) {
    int e = base + i;
    if (e < EE) {
      int d = ei[EE + e];
      int s = ei[e];
      int p = atomicAdd(&cur[d >> 9], 1);
      ebuf[p] = make_int2(s, d);
    }
  }
}

// merged bdeg2 + binscatter (R16-verified): histogram -> scan -> row_ptr ->
// cursors -> scatter col, all in one block per 512-node bucket.
__global__ void k_bcsr(const int2* __restrict__ ebuf, const int* __restrict__ eoff,
                       int* __restrict__ row_ptr, int* __restrict__ col, int n) {
  __shared__ int dl[512];
  __shared__ int ps[256];
  int b = blockIdx.x, tid = threadIdx.x;
  int d0 = b << 9;
  dl[tid] = 0; dl[tid + 256] = 0;
  __syncthreads();
  int s0 = eoff[b * EB];
  int s1 = (b + 1 < NBUK) ? eoff[(b + 1) * EB] : EE;
  for (int e = s0 + tid; e < s1; e += 256) atomicAdd(&dl[ebuf[e].y - d0], 1);
  __syncthreads();
  int a0 = dl[2 * tid], a1 = dl[2 * tid + 1];
  ps[tid] = a0 + a1;
  __syncthreads();
  for (int off = 1; off < 256; off <<= 1) {
    int x = 0;
    if (tid >= off) x = ps[tid - off];
    __syncthreads();
    if (tid >= off) ps[tid] += x;
    __syncthreads();
  }
  int epair = ps[tid] - (a0 + a1);     // exclusive prefix of this pair
  int r0 = s0 + epair;
  int r1 = r0 + a0;
  int i0 = d0 + 2 * tid;
  if (i0 <= n) row_ptr[i0] = r0;       // covers row_ptr[n] = EE
  if (i0 + 1 <= n) row_ptr[i0 + 1] = r1;
  __syncthreads();
  dl[2 * tid] = r0;                    // reuse histogram LDS as cursors
  dl[2 * tid + 1] = r1;
  __syncthreads();
  for (int e = s0 + tid; e < s1; e += 256) {
    int2 sd = ebuf[e];
    int p = atomicAdd(&dl[sd.y - d0], 1);
    col[p] = sd.x;
  }
}

// ---------------- projections via MFMA ----------------
template <int F, typename TIN>
__global__ __launch_bounds__(256) void k_gemm_mfma(
    const TIN* __restrict__ X,
    const float* __restrict__ Wq, const float* __restrict__ bq,
    const float* __restrict__ Wk, const float* __restrict__ bk,
    const float* __restrict__ Wv, const float* __restrict__ bv,
    const float* __restrict__ Ws, const float* __restrict__ bs,
    __half* __restrict__ qh, __half* __restrict__ kh, __half* __restrict__ vh,
    __half* __restrict__ Bh, int n) {
  constexpr int KH = (F + 31) / 32;
  constexpr int S = KH * 32 + 8;
  __shared__ _Float16 xs[64 * S];
  int tid = threadIdx.x;
  int lane = tid & 63;
  int wv = tid >> 6;
  int quad = lane >> 4;
  int li = lane & 15;
  int node0 = blockIdx.x * 64;

  if constexpr (std::is_same<TIN, float>::value) {
    constexpr int F4 = F / 4;
    constexpr int CNT = 64 * F4 / 256;
#pragma unroll
    for (int i = 0; i < CNT; i++) {
      int idx = tid + i * 256;
      int nd = idx / F4;
      int kb = (idx % F4) * 4;
      float4 p;
      if (node0 + nd < n) p = *(const float4*)(X + (size_t)(node0 + nd) * F + kb);
      else p = make_float4(0.f, 0.f, 0.f, 0.f);
      _Float16* d = xs + nd * S + kb;
      d[0] = (_Float16)p.x; d[1] = (_Float16)p.y;
      d[2] = (_Float16)p.z; d[3] = (_Float16)p.w;
    }
    if (F == 16) {  // zero-pad k in [16,32)
      int nd = tid >> 2;
      int kb = 16 + (tid & 3) * 4;
      _Float16* d = xs + nd * S + kb;
      d[0] = 0; d[1] = 0; d[2] = 0; d[3] = 0;
    }
  } else {
    constexpr int F8 = F / 8;
    constexpr int CNT = 64 * F8 / 256;
#pragma unroll
    for (int i = 0; i < CNT; i++) {
      int idx = tid + i * 256;
      int nd = idx / F8;
      int kb = (idx % F8) * 8;
      f16x8 p = {};
      if (node0 + nd < n)
        p = *(const f16x8*)((const _Float16*)X + (size_t)(node0 + nd) * F + kb);
      *(f16x8*)(xs + nd * S + kb) = p;
    }
  }

  const float* W; const float* bias;
  if (wv == 0)      { W = Wq; bias = bq; }
  else if (wv == 1) { W = Wk; bias = bk; }
  else if (wv == 2) { W = Wv; bias = bv; }
  else              { W = Ws; bias = bs; }

  f16x8 bf[4][KH];
#pragma unroll
  for (int ns = 0; ns < 4; ns++)
#pragma unroll
    for (int kh2 = 0; kh2 < KH; kh2++)
#pragma unroll
      for (int j = 0; j < 8; j++) {
        int kidx = kh2 * 32 + quad * 8 + j;
        bf[ns][kh2][j] = (kidx < F)
            ? (_Float16)W[(size_t)kidx * 64 + ns * 16 + li] : (_Float16)0.f;
      }
  float blv[4];
#pragma unroll
  for (int ns = 0; ns < 4; ns++) blv[ns] = bias[ns * 16 + li];

  __syncthreads();

  f16x8 af[4][KH];
#pragma unroll
  for (int ms = 0; ms < 4; ms++)
#pragma unroll
    for (int kh2 = 0; kh2 < KH; kh2++)
      af[ms][kh2] = *(const f16x8*)(xs + (ms * 16 + li) * S + kh2 * 32 + quad * 8);

  f32x4 acc[4][4];
#pragma unroll
  for (int ms = 0; ms < 4; ms++)
#pragma unroll
    for (int ns = 0; ns < 4; ns++) {
      float b = blv[ns];
      acc[ms][ns] = (f32x4){b, b, b, b};
    }
#pragma unroll
  for (int kh2 = 0; kh2 < KH; kh2++)
#pragma unroll
    for (int ms = 0; ms < 4; ms++)
#pragma unroll
      for (int ns = 0; ns < 4; ns++)
        acc[ms][ns] = __builtin_amdgcn_mfma_f32_16x16x32_f16(
            af[ms][kh2], bf[ns][kh2], acc[ms][ns], 0, 0, 0);

  __half* outh = (wv == 0) ? qh : (wv == 1) ? kh : (wv == 2) ? vh : Bh;
#pragma unroll
  for (int ms = 0; ms < 4; ms++)
#pragma unroll
    for (int ns = 0; ns < 4; ns++) {
      int colc = ns * 16 + li;
#pragma unroll
      for (int r = 0; r < 4; r++) {
        int node = node0 + ms * 16 + quad * 4 + r;
        if (node < n)
          outh[(size_t)node * 64 + colc] = __float2half(acc[ms][ns][r]);
      }
    }
}

// ---------------- fused attention, two internal phases (R18) ----------------
// Block = 64 consecutive dsts. Chunked at 1024 edges (M ~ 768, so normally
// one chunk; the chunk loop is the correctness guarantee for any M).
// Phase A (32 groups x 8 lanes, branch-free): dst via 6-step branchless
// binary search in LDS rpl; gather k row (128B/group); q from global
// (dst-sorted -> L1-hot); exp -> wbuf[LDS]. No carried deps -> pipelines.
// Phase B (8 groups x 32 lanes, group owns 8 contiguous dsts): per edge
// 2 LDS broadcasts + one coalesced 128B v load + fma into REGISTER
// accumulators. No shfl, no atomics, no LDS accumulator; denom computed
// redundantly per lane. exp w/o max-subtract is associative across chunks.
__global__ __launch_bounds__(256) void k_fused(
    const __half* __restrict__ qh, const __half* __restrict__ kh,
    const __half* __restrict__ vh, const int* __restrict__ row_ptr,
    const int* __restrict__ col, __half* __restrict__ Bh, int n) {
  __shared__ float wbuf[1024];
  __shared__ int scbuf[1024];
  __shared__ int rpl[65];
  int tid = threadIdx.x;
  int d0 = blockIdx.x * 64;
  int ndst = n - d0; if (ndst > 64) ndst = 64;

  if (tid < 65) {
    int dd = d0 + tid; if (dd > n) dd = n;
    rpl[tid] = row_ptr[dd];
  }
  __syncthreads();
  int e0 = rpl[0], e1 = rpl[ndst];

  int gid = tid >> 5, hl = tid & 31;   // phase B: 8 groups x 32 lanes
  int ag = tid >> 3, aj = tid & 7;     // phase A: 32 groups x 8 lanes

  float2 acc[8];
  float den[8];
#pragma unroll
  for (int k = 0; k < 8; k++) { acc[k] = make_float2(0.f, 0.f); den[k] = 0.f; }

  for (int c0 = e0; c0 < e1; c0 += 1024) {
    int cn = e1 - c0; if (cn > 1024) cn = 1024;
    // stage col chunk (coalesced)
#pragma unroll
    for (int s = 0; s < 4; s++) {
      int i = tid + s * 256;
      if (i < cn) scbuf[i] = col[c0 + i];
    }
    __syncthreads();

    // ---- phase A: scores ----
    for (int i = ag; i < cn; i += 32) {
      int e = c0 + i;
      int lo = 0;                      // branchless search: rpl[lo]<=e<rpl[lo+1]
#pragma unroll
      for (int st = 32; st >= 1; st >>= 1) {
        int nxt = lo + st;
        if (rpl[nxt] <= e) lo = nxt;   // rpl[>ndst]=EE > e, safe
      }
      int src = scbuf[i];
      f16x8 kv = *(const f16x8*)((const _Float16*)kh + (size_t)src * 64 + aj * 8);
      f16x8 qv = *(const f16x8*)((const _Float16*)qh + (size_t)(d0 + lo) * 64 + aj * 8);
      float ds = 0.f;
#pragma unroll
      for (int u = 0; u < 8; u++) ds += (float)qv[u] * (float)kv[u];
      ds += __shfl_xor(ds, 1, 64);
      ds += __shfl_xor(ds, 2, 64);
      ds += __shfl_xor(ds, 4, 64);
      if (aj == 0) wbuf[i] = __expf(fminf(ds * 0.125f, 60.f));  // 1/sqrt(64)
    }
    __syncthreads();

    // ---- phase B: aggregate; group gid owns dsts gid*8 .. gid*8+7 ----
#pragma unroll
    for (int k = 0; k < 8; k++) {
      int dl = gid * 8 + k;
      if (dl < ndst) {
        int lo2 = rpl[dl];     if (lo2 < c0) lo2 = c0;
        int hi2 = rpl[dl + 1]; if (hi2 > c0 + cn) hi2 = c0 + cn;
        int i = lo2 - c0, iend = hi2 - c0;
        for (; i + 2 <= iend; i += 2) {
          float w0 = wbuf[i];     int s0 = scbuf[i];
          float w1 = wbuf[i + 1]; int s1 = scbuf[i + 1];
          float2 f0 = __half22float2(*(const __half2*)(vh + (size_t)s0 * 64 + hl * 2));
          float2 f1 = __half22float2(*(const __half2*)(vh + (size_t)s1 * 64 + hl * 2));
          acc[k].x = fmaf(w0, f0.x, acc[k].x); acc[k].y = fmaf(w0, f0.y, acc[k].y);
          acc[k].x = fmaf(w1, f1.x, acc[k].x); acc[k].y = fmaf(w1, f1.y, acc[k].y);
          den[k] += w0 + w1;
        }
        if (i < iend) {
          float w0 = wbuf[i]; int s0 = scbuf[i];
          float2 f0 = __half22float2(*(const __half2*)(vh + (size_t)s0 * 64 + hl * 2));
          acc[k].x = fmaf(w0, f0.x, acc[k].x); acc[k].y = fmaf(w0, f0.y, acc[k].y);
          den[k] += w0;
        }
      }
    }
    __syncthreads();   // before next chunk overwrites wbuf/scbuf
  }

  // write out (B pre-holds the skip term)
#pragma unroll
  for (int k = 0; k < 8; k++) {
    int dl = gid * 8 + k;
    if (dl < ndst) {
      __half2* bp = (__half2*)(Bh + (size_t)(d0 + dl) * 64) + hl;
      float2 old = __half22float2(*bp);
      float inv = 1.f / (den[k] + 1e-16f);
      old.x += acc[k].x * inv;
      old.y += acc[k].y * inv;
      *bp = __float22half2_rn(old);
    }
  }
}

// ---------------- pooling ----------------
__global__ __launch_bounds__(256) void k_pool(
    const __half* __restrict__ H, const int* __restrict__ batch,
    float* __restrict__ pooled, int* __restrict__ cnt, int n) {
  int lane = threadIdx.x & 63;
  int w = threadIdx.x >> 6;
  int n0 = blockIdx.x * 64 + w * 16;
  float acc = 0.f;
  int cur = -1, nc = 0;
  for (int i = 0; i < 16; i++) {
    int node = n0 + i;
    if (node >= n) break;
    int g = batch[node];
    if (g != cur) {
      if (cur >= 0) {
        atomicAdd(&pooled[cur * 64 + lane], acc);
        if (lane == 0) atomicAdd(&cnt[cur], nc);
      }
      cur = g;
      acc = 0.f;
      nc = 0;
    }
    acc += __half2float(H[(size_t)node * 64 + lane]);
    nc++;
  }
  if (cur >= 0) {
    atomicAdd(&pooled[cur * 64 + lane], acc);
    if (lane == 0) atomicAdd(&cnt[cur], nc);
  }
}

__global__ void k_out(const float* __restrict__ pooled, const int* __restrict__ cnt,
                      const float* __restrict__ Wf, const float* __restrict__ bf,
                      float* __restrict__ out) {
  int g = blockIdx.x;
  int lane = threadIdx.x;
  int c = cnt[g];
  float cf = (float)(c > 1 ? c : 1);
  float mean = pooled[g * 64 + lane] / cf;
#pragma unroll
  for (int o = 0; o < OUTF; o++) {
    float p = wave_reduce_sum(mean * Wf[lane * OUTF + o]);
    if (lane == 0) out[g * OUTF + o] = p + bf[o];
  }
}

// ---------------- launch ----------------
extern "C" void kernel_launch(void* const* d_in, const int* in_sizes, int n_in,
                              void* d_out, int out_size, void* d_ws, size_t ws_size,
                              hipStream_t stream) {
  const float* x   = (const float*)d_in[0];
  const int* ei    = (const int*)d_in[1];
  const int* batch = (const int*)d_in[2];
  const float *Wq0 = (const float*)d_in[3],  *bq0 = (const float*)d_in[4];
  const float *Wk0 = (const float*)d_in[5],  *bk0 = (const float*)d_in[6];
  const float *Wv0 = (const float*)d_in[7],  *bv0 = (const float*)d_in[8];
  const float *Ws0 = (const float*)d_in[9],  *bs0 = (const float*)d_in[10];
  const float *Wqh = (const float*)d_in[11], *bqh = (const float*)d_in[12];
  const float *Wkh = (const float*)d_in[13], *bkh = (const float*)d_in[14];
  const float *Wvh = (const float*)d_in[15], *bvh = (const float*)d_in[16];
  const float *Wsh = (const float*)d_in[17], *bsh = (const float*)d_in[18];
  const float *Wf  = (const float*)d_in[19], *bf  = (const float*)d_in[20];

  __half* qh = (__half*)d_ws;
  __half* kh = qh + (size_t)NN * 64;
  __half* vh = kh + (size_t)NN * 64;
  __half* B0 = vh + (size_t)NN * 64;
  __half* B1 = B0 + (size_t)NN * 64;
  float* pooled = (float*)(B1 + (size_t)NN * 64);
  int* cnt     = (int*)(pooled + GG * 64);
  int* row_ptr = cnt + GG;
  int* col     = row_ptr + NN + 2;
  int* hblk    = col + EE;
  int* incl2   = hblk + LEN;
  int* bsum2   = incl2 + LEN;
  int* boff2   = bsum2 + 128;
  int* eoff    = boff2 + 128;
  int2* ebuf   = (int2*)((((uintptr_t)(eoff + LEN)) + 15) & ~(uintptr_t)15);

  hipMemsetAsync(pooled, 0, (GG * 64 + GG) * sizeof(float), stream);

  // bucketed CSR build (once per call; reused by all 4 layers)
  k_bh<<<EB, 256, 0, stream>>>(ei, hblk);
  int nb2 = (LEN + 1023) / 1024;
  k_scan1<<<nb2, 256, 0, stream>>>(hblk, incl2, bsum2, LEN);
  k_scan2<<<1, 64, 0, stream>>>(bsum2, boff2, nb2);
  k_eoff<<<(LEN + 255) / 256, 256, 0, stream>>>(incl2, boff2, hblk, eoff, LEN);
  k_binwrite<<<EB, 256, 0, stream>>>(ei, eoff, ebuf);
  k_bcsr<<<NBUK, 256, 0, stream>>>(ebuf, eoff, row_ptr, col, NN);

  int gg = (NN + 63) / 64;
  int ga = (NN + 63) / 64;   // 64 dsts per block

  // layer 0 (F_IN=16, fp32 input)
  k_gemm_mfma<FIN, float><<<gg, 256, 0, stream>>>(
      x, Wq0, bq0, Wk0, bk0, Wv0, bv0, Ws0, bs0, qh, kh, vh, B0, NN);
  k_fused<<<ga, 256, 0, stream>>>(qh, kh, vh, row_ptr, col, B0, NN);

  // hidden layers (H=64, fp16 h), ping-pong B0 <-> B1
  const __half* hin = B0;
  __half* hout = B1;
  for (int i = 0; i < NHID; i++) {
    k_gemm_mfma<HH, __half><<<gg, 256, 0, stream>>>(
        hin, Wqh + i * 4096, bqh + i * 64,
        Wkh + i * 4096, bkh + i * 64,
        Wvh + i * 4096, bvh + i * 64,
        Wsh + i * 4096, bsh + i * 64,
        qh, kh, vh, hout, NN);
    k_fused<<<ga, 256, 0, stream>>>(qh, kh, vh, row_ptr, col, hout, NN);
    __half* t = (__half*)hin; hin = hout; hout = t;
  }

  k_pool<<<(NN + 63) / 64, 256, 0, stream>>>(hin, batch, pooled, cnt, NN);
  k_out<<<GG, 64, 0, stream>>>(pooled, cnt, Wf, bf, (float*)d_out);
}